// Round 3
// baseline (598.727 us; speedup 1.0000x reference)
//
#include <hip/hip_runtime.h>

#define NUM_E 1024
#define DIM 64
#define NROWS 65536                  // 64*32*32
#define OUT0_SIZE 4194304            // 64*64*32*32
#define OUT1_OFF OUT0_SIZE
#define LOSS_OFF (OUT0_SIZE + 65536) // 4259840

// Bit-exact replica of numpy's pairwise_sum base case for n=64 contiguous
// fp32 applied to sum(x*x): products are rounded FIRST (numpy materializes
// the x*x temp), then 8 accumulators, then the fixed combine tree.
// contract(off) is mandatory: HIP's default -ffp-contract=fast would fuse
// p = x*x; r += p into fma and change the rounding vs numpy.
__device__ __forceinline__ float np_sumsq64(const float* __restrict__ x) {
#pragma clang fp contract(off)
    float r[8];
#pragma unroll
    for (int j = 0; j < 8; ++j) r[j] = x[j] * x[j];
#pragma unroll
    for (int i = 8; i < 64; i += 8) {
#pragma unroll
        for (int j = 0; j < 8; ++j) {
            float p = x[i + j] * x[i + j];
            r[j] = r[j] + p;
        }
    }
    return ((r[0] + r[1]) + (r[2] + r[3])) + ((r[4] + r[5]) + (r[6] + r[7]));
}

// Kernel 1: E_k = np.sum(e_k*e_k) in numpy order; zero the loss slot
// (d_out is re-poisoned to 0xAA before every timed launch).
__global__ __launch_bounds__(256) void vq_prep_kernel(const float* __restrict__ e,
                                                      float* __restrict__ En,
                                                      float* __restrict__ out) {
    const int k = blockIdx.x * 256 + threadIdx.x;   // grid covers 1024 exactly
    if (k == 0) out[LOSS_OFF] = 0.0f;
    float xr[DIM];
    const float4* ep = (const float4*)(e + (size_t)k * DIM);
#pragma unroll
    for (int i = 0; i < 16; ++i) {
        float4 v = ep[i];
        xr[4*i+0] = v.x; xr[4*i+1] = v.y; xr[4*i+2] = v.z; xr[4*i+3] = v.w;
    }
    En[k] = np_sumsq64(xr);
}

// Kernel 2: one thread per row. Replicates the np fp32 pipeline bit-exactly:
//   A_n   = np pairwise sum of zf*zf
//   M_nk  = sgemm dot: sequential fma chain k-order 0..63 from acc=0
//   score = (A - 2*M) + E      (left-assoc, 2*M exact)
//   argmin: first index of strict minimum (ascending k, strict <)
__global__ __launch_bounds__(256) void vq_main_kernel(const float* __restrict__ z,
                                                      const float* __restrict__ e,
                                                      const float* __restrict__ En,
                                                      float* __restrict__ out) {
    const int n = blockIdx.x * 256 + threadIdx.x;   // grid covers NROWS exactly

    float zr[DIM];
    {
        const float4* zp = (const float4*)(z + (size_t)n * DIM);
#pragma unroll
        for (int i = 0; i < 16; ++i) {
            float4 v = zp[i];
            zr[4*i+0] = v.x; zr[4*i+1] = v.y; zr[4*i+2] = v.z; zr[4*i+3] = v.w;
        }
    }

    const float A = np_sumsq64(zr);

    float best = 3.4e38f;
    int bestk = 0;
#pragma unroll 4
    for (int k = 0; k < NUM_E; ++k) {
        const float* er = e + (size_t)k * DIM;      // wave-uniform -> scalar loads
        float m = 0.0f;
#pragma unroll
        for (int i = 0; i < DIM; ++i)
            m = fmaf(er[i], zr[i], m);              // sequential chain = sgemm microkernel
        float s;
        {
#pragma clang fp contract(off)
            float twoM = 2.0f * m;                  // exact (x2)
            float t = A - twoM;                     // rounds at ulp(~64) -- the ref's grid
            s = t + En[k];
        }
        if (s < best) { best = s; bestk = k; }      // strict < => first-index tie-break
    }

    // ---- epilogue (thresholds on out0/out2 are vacuous; keep it simple) ----
    const int b  = n >> 10;       // H*W = 1024
    const int hw = n & 1023;
    const float* er = e + (size_t)bestk * DIM;
    float* o0 = out + (size_t)b * 65536 + hw;       // out0[b, d, hw]
    float lsum = 0.0f;
#pragma unroll
    for (int d = 0; d < DIM; ++d) {
        float ev = er[d];                           // codebook L1/L2-hot gather
        o0[(size_t)d * 1024] = ev;                  // coalesced across lanes per d
        float df = ev - zr[d];
        lsum = fmaf(df, df, lsum);
    }
    out[OUT1_OFF + n] = (float)bestk;

    // loss: wave shuffle reduce -> LDS across 4 waves -> one atomicAdd per block
#pragma unroll
    for (int off = 32; off > 0; off >>= 1)
        lsum += __shfl_down(lsum, off, 64);
    __shared__ float wsum[4];
    const int lane = threadIdx.x & 63;
    const int wid  = threadIdx.x >> 6;
    if (lane == 0) wsum[wid] = lsum;
    __syncthreads();
    if (threadIdx.x == 0) {
        float bs = wsum[0] + wsum[1] + wsum[2] + wsum[3];
        // loss = (0.25 + 1.0) * mean(diff^2) over 4194304 elements
        atomicAdd(&out[LOSS_OFF], bs * (1.25f / 4194304.0f));
    }
}

extern "C" void kernel_launch(void* const* d_in, const int* in_sizes, int n_in,
                              void* d_out, int out_size, void* d_ws, size_t ws_size,
                              hipStream_t stream) {
    const float* z = (const float*)d_in[0];       // [65536, 64] fp32
    const float* e = (const float*)d_in[1];       // [1024, 64] fp32
    float* out = (float*)d_out;
    float* En  = (float*)d_ws;                    // 1024 fp32 norms (4 KB scratch)

    vq_prep_kernel<<<NUM_E / 256, 256, 0, stream>>>(e, En, out);
    vq_main_kernel<<<NROWS / 256, 256, 0, stream>>>(z, e, En, out);
}

// Round 4
// 234.692 us; speedup vs baseline: 2.5511x; 2.5511x over previous
//
#include <hip/hip_runtime.h>

#define NUM_E 1024
#define DIM 64
#define NROWS 65536                  // 64*32*32
#define OUT0_SIZE 4194304            // 64*64*32*32
#define OUT1_OFF OUT0_SIZE
#define LOSS_OFF (OUT0_SIZE + 65536) // 4259840
#define KSPLIT 4
#define KCHUNK (NUM_E / KSPLIT)      // 256 codes per slice

// Bit-exact replica of numpy's pairwise_sum base case (n=64, contiguous fp32)
// applied to sum(x*x): products rounded first (numpy materializes x*x), 8
// accumulators, fixed combine tree. contract(off) is mandatory.
__device__ __forceinline__ float np_sumsq64(const float* __restrict__ x) {
#pragma clang fp contract(off)
    float r[8];
#pragma unroll
    for (int j = 0; j < 8; ++j) r[j] = x[j] * x[j];
#pragma unroll
    for (int i = 8; i < 64; i += 8) {
#pragma unroll
        for (int j = 0; j < 8; ++j) {
            float p = x[i + j] * x[i + j];
            r[j] = r[j] + p;
        }
    }
    return ((r[0] + r[1]) + (r[2] + r[3])) + ((r[4] + r[5]) + (r[6] + r[7]));
}

// Kernel 1: E_k = np.sum(e_k*e_k) in numpy order; zero the loss slot
// (d_out is re-poisoned to 0xAA before every timed launch).
__global__ __launch_bounds__(256) void vq_prep_kernel(const float* __restrict__ e,
                                                      float* __restrict__ En,
                                                      float* __restrict__ out) {
    const int k = blockIdx.x * 256 + threadIdx.x;   // grid covers 1024 exactly
    if (k == 0) out[LOSS_OFF] = 0.0f;
    float xr[DIM];
    const float4* ep = (const float4*)(e + (size_t)k * DIM);
#pragma unroll
    for (int i = 0; i < 16; ++i) {
        float4 v = ep[i];
        xr[4*i+0] = v.x; xr[4*i+1] = v.y; xr[4*i+2] = v.z; xr[4*i+3] = v.w;
    }
    En[k] = np_sumsq64(xr);
}

// Kernel 2 (scan): 4 blocks per 256 rows; block's q picks a k-slice (uniform
// per block -> e loads stay scalar). Each thread: full np-exact score for its
// (n,k) pairs, tracks slice-local argmin. 4096 waves -> 4 waves/SIMD.
__global__ __launch_bounds__(256, 4) void vq_scan_kernel(const float* __restrict__ z,
                                                         const float* __restrict__ e,
                                                         const float* __restrict__ En,
                                                         float* __restrict__ sbest,
                                                         int* __restrict__ kbest) {
    const int bid = blockIdx.x;
    const int q = bid & (KSPLIT - 1);
    const int n = (bid >> 2) * 256 + threadIdx.x;

    float zr[DIM];                                   // must stay in VGPRs (128-cap)
    {
        const float4* zp = (const float4*)(z + (size_t)n * DIM);
#pragma unroll
        for (int i = 0; i < 16; ++i) {
            float4 v = zp[i];
            zr[4*i+0] = v.x; zr[4*i+1] = v.y; zr[4*i+2] = v.z; zr[4*i+3] = v.w;
        }
    }
    const float A = np_sumsq64(zr);

    const int k0 = q * KCHUNK;
    float best = 3.4e38f;
    int bk = k0;
#pragma unroll 2
    for (int kk = 0; kk < KCHUNK; ++kk) {
        const int k = k0 + kk;
        const float* er = e + (size_t)k * DIM;       // wave-uniform -> s_load
        float m = 0.0f;
#pragma unroll
        for (int i = 0; i < DIM; ++i)
            m = fmaf(er[i], zr[i], m);               // sequential chain = sgemm order
        float s;
        {
#pragma clang fp contract(off)
            float twoM = 2.0f * m;                   // exact
            float t = A - twoM;
            s = t + En[k];
        }
        if (s < best) { best = s; bk = k; }          // strict < => first-index
    }
    sbest[(size_t)n * KSPLIT + q] = best;
    kbest[(size_t)n * KSPLIT + q] = bk;
}

// Kernel 3 (finish): reduce 4 slices (ascending q = ascending k, strict <
// keeps the first index), gather codebook row, write outputs + fused loss.
__global__ __launch_bounds__(256) void vq_finish_kernel(const float* __restrict__ z,
                                                        const float* __restrict__ e,
                                                        const float* __restrict__ sbest,
                                                        const int* __restrict__ kbest,
                                                        float* __restrict__ out) {
    const int n = blockIdx.x * 256 + threadIdx.x;

    float best = sbest[(size_t)n * KSPLIT];
    int bk = kbest[(size_t)n * KSPLIT];
#pragma unroll
    for (int q = 1; q < KSPLIT; ++q) {
        float s = sbest[(size_t)n * KSPLIT + q];
        int k2 = kbest[(size_t)n * KSPLIT + q];
        if (s < best) { best = s; bk = k2; }         // ties keep lower q (= lower k)
    }

    const int b  = n >> 10;       // H*W = 1024
    const int hw = n & 1023;
    const float* er = e + (size_t)bk * DIM;
    const float* zrp = z + (size_t)n * DIM;
    float* o0 = out + (size_t)b * 65536 + hw;        // out0[b, d, hw]
    float lsum = 0.0f;
#pragma unroll
    for (int d = 0; d < DIM; ++d) {
        float ev = er[d];                            // codebook L1/L2-hot gather
        o0[(size_t)d * 1024] = ev;                   // coalesced across lanes per d
        float df = ev - zrp[d];
        lsum = fmaf(df, df, lsum);
    }
    out[OUT1_OFF + n] = (float)bk;

#pragma unroll
    for (int off = 32; off > 0; off >>= 1)
        lsum += __shfl_down(lsum, off, 64);
    __shared__ float wsum[4];
    const int lane = threadIdx.x & 63;
    const int wid  = threadIdx.x >> 6;
    if (lane == 0) wsum[wid] = lsum;
    __syncthreads();
    if (threadIdx.x == 0) {
        float bs = wsum[0] + wsum[1] + wsum[2] + wsum[3];
        // loss = (0.25 + 1.0) * mean(diff^2) over 4194304 elements
        atomicAdd(&out[LOSS_OFF], bs * (1.25f / 4194304.0f));
    }
}

extern "C" void kernel_launch(void* const* d_in, const int* in_sizes, int n_in,
                              void* d_out, int out_size, void* d_ws, size_t ws_size,
                              hipStream_t stream) {
    const float* z = (const float*)d_in[0];       // [65536, 64] fp32
    const float* e = (const float*)d_in[1];       // [1024, 64] fp32
    float* out = (float*)d_out;

    // workspace layout: En (4 KB) | sbest (1 MB) | kbest (1 MB)
    float* En    = (float*)d_ws;
    float* sbest = (float*)((char*)d_ws + 4096);
    int*   kbest = (int*)((char*)d_ws + 4096 + (size_t)NROWS * KSPLIT * 4);

    vq_prep_kernel<<<NUM_E / 256, 256, 0, stream>>>(e, En, out);
    vq_scan_kernel<<<(NROWS / 256) * KSPLIT, 256, 0, stream>>>(z, e, En, sbest, kbest);
    vq_finish_kernel<<<NROWS / 256, 256, 0, stream>>>(z, e, sbest, kbest, out);
}

// Round 5
// 234.189 us; speedup vs baseline: 2.5566x; 1.0021x over previous
//
#include <hip/hip_runtime.h>

#define NUM_E 1024
#define DIM 64
#define NROWS 65536                  // 64*32*32
#define OUT0_SIZE 4194304            // 64*64*32*32
#define OUT1_OFF OUT0_SIZE
#define LOSS_OFF (OUT0_SIZE + 65536) // 4259840
#define KSPLIT 4
#define KCHUNK (NUM_E / KSPLIT)      // 256 codes per slice

// Bit-exact replica of numpy's pairwise_sum base case (n=64, contiguous fp32)
// applied to sum(x*x): products rounded first (numpy materializes x*x), 8
// accumulators, fixed combine tree. contract(off) is mandatory.
__device__ __forceinline__ float np_sumsq64(const float* __restrict__ x) {
#pragma clang fp contract(off)
    float r[8];
#pragma unroll
    for (int j = 0; j < 8; ++j) r[j] = x[j] * x[j];
#pragma unroll
    for (int i = 8; i < 64; i += 8) {
#pragma unroll
        for (int j = 0; j < 8; ++j) {
            float p = x[i + j] * x[i + j];
            r[j] = r[j] + p;
        }
    }
    return ((r[0] + r[1]) + (r[2] + r[3])) + ((r[4] + r[5]) + (r[6] + r[7]));
}

// Kernel 1: E_k = np.sum(e_k*e_k) in numpy order; zero the loss slot
// (d_out is re-poisoned to 0xAA before every timed launch).
__global__ __launch_bounds__(256) void vq_prep_kernel(const float* __restrict__ e,
                                                      float* __restrict__ En,
                                                      float* __restrict__ out) {
    const int k = blockIdx.x * 256 + threadIdx.x;   // grid covers 1024 exactly
    if (k == 0) out[LOSS_OFF] = 0.0f;
    float xr[DIM];
    const float4* ep = (const float4*)(e + (size_t)k * DIM);
#pragma unroll
    for (int i = 0; i < 16; ++i) {
        float4 v = ep[i];
        xr[4*i+0] = v.x; xr[4*i+1] = v.y; xr[4*i+2] = v.z; xr[4*i+3] = v.w;
    }
    En[k] = np_sumsq64(xr);
}

// Kernel 2 (scan): 4 blocks per 256 rows; block's q picks a k-slice (uniform
// per block -> e loads stay scalar). z row PINNED in VGPRs via asm so the
// k-loop is pure VALU (R4: compiler rematerialized z loads into the loop,
// VGPR_Count=40, co-limited by L1 -> 179us at VALUBusy 70%).
__global__ __launch_bounds__(256, 4) void vq_scan_kernel(const float* __restrict__ z,
                                                         const float* __restrict__ e,
                                                         const float* __restrict__ En,
                                                         float* __restrict__ sbest,
                                                         int* __restrict__ kbest) {
    const int bid = blockIdx.x;
    const int q = bid & (KSPLIT - 1);
    const int n = (bid >> 2) * 256 + threadIdx.x;

    float zr[DIM];
    {
        const float4* zp = (const float4*)(z + (size_t)n * DIM);
#pragma unroll
        for (int i = 0; i < 16; ++i) {
            float4 v = zp[i];
            zr[4*i+0] = v.x; zr[4*i+1] = v.y; zr[4*i+2] = v.z; zr[4*i+3] = v.w;
        }
    }
    // Pin all 64 z values in VGPRs: opaque to the compiler -> cannot be
    // rematerialized/re-loaded inside the k-loop. ~64+30 regs < 128 cap.
#pragma unroll
    for (int i = 0; i < DIM; ++i)
        asm volatile("" : "+v"(zr[i]));

    const float A = np_sumsq64(zr);

    const int k0 = q * KCHUNK;
    float best = 3.4e38f;
    int bk = k0;
#pragma unroll 2
    for (int kk = 0; kk < KCHUNK; ++kk) {
        const int k = k0 + kk;
        const float* er = e + (size_t)k * DIM;       // wave-uniform -> s_load
        float m = 0.0f;
#pragma unroll
        for (int i = 0; i < DIM; ++i)
            m = fmaf(er[i], zr[i], m);               // sequential chain = sgemm order
        float s;
        {
#pragma clang fp contract(off)
            float twoM = 2.0f * m;                   // exact
            float t = A - twoM;
            s = t + En[k];
        }
        if (s < best) { best = s; bk = k; }          // strict < => first-index
    }
    sbest[(size_t)n * KSPLIT + q] = best;
    kbest[(size_t)n * KSPLIT + q] = bk;
}

// Kernel 3 (finish): reduce 4 slices (ascending q = ascending k, strict <
// keeps the first index), gather codebook row, write outputs + fused loss.
__global__ __launch_bounds__(256) void vq_finish_kernel(const float* __restrict__ z,
                                                        const float* __restrict__ e,
                                                        const float* __restrict__ sbest,
                                                        const int* __restrict__ kbest,
                                                        float* __restrict__ out) {
    const int n = blockIdx.x * 256 + threadIdx.x;

    float best = sbest[(size_t)n * KSPLIT];
    int bk = kbest[(size_t)n * KSPLIT];
#pragma unroll
    for (int q = 1; q < KSPLIT; ++q) {
        float s = sbest[(size_t)n * KSPLIT + q];
        int k2 = kbest[(size_t)n * KSPLIT + q];
        if (s < best) { best = s; bk = k2; }         // ties keep lower q (= lower k)
    }

    const int b  = n >> 10;       // H*W = 1024
    const int hw = n & 1023;
    const float* er = e + (size_t)bk * DIM;
    const float* zrp = z + (size_t)n * DIM;
    float* o0 = out + (size_t)b * 65536 + hw;        // out0[b, d, hw]
    float lsum = 0.0f;
#pragma unroll
    for (int d = 0; d < DIM; ++d) {
        float ev = er[d];                            // codebook L2-hot gather
        o0[(size_t)d * 1024] = ev;                   // coalesced across lanes per d
        float df = ev - zrp[d];
        lsum = fmaf(df, df, lsum);
    }
    out[OUT1_OFF + n] = (float)bk;

#pragma unroll
    for (int off = 32; off > 0; off >>= 1)
        lsum += __shfl_down(lsum, off, 64);
    __shared__ float wsum[4];
    const int lane = threadIdx.x & 63;
    const int wid  = threadIdx.x >> 6;
    if (lane == 0) wsum[wid] = lsum;
    __syncthreads();
    if (threadIdx.x == 0) {
        float bs = wsum[0] + wsum[1] + wsum[2] + wsum[3];
        // loss = (0.25 + 1.0) * mean(diff^2) over 4194304 elements
        atomicAdd(&out[LOSS_OFF], bs * (1.25f / 4194304.0f));
    }
}

extern "C" void kernel_launch(void* const* d_in, const int* in_sizes, int n_in,
                              void* d_out, int out_size, void* d_ws, size_t ws_size,
                              hipStream_t stream) {
    const float* z = (const float*)d_in[0];       // [65536, 64] fp32
    const float* e = (const float*)d_in[1];       // [1024, 64] fp32
    float* out = (float*)d_out;

    // workspace layout: En (4 KB) | sbest (1 MB) | kbest (1 MB)
    float* En    = (float*)d_ws;
    float* sbest = (float*)((char*)d_ws + 4096);
    int*   kbest = (int*)((char*)d_ws + 4096 + (size_t)NROWS * KSPLIT * 4);

    vq_prep_kernel<<<NUM_E / 256, 256, 0, stream>>>(e, En, out);
    vq_scan_kernel<<<(NROWS / 256) * KSPLIT, 256, 0, stream>>>(z, e, En, sbest, kbest);
    vq_finish_kernel<<<NROWS / 256, 256, 0, stream>>>(z, e, sbest, kbest, out);
}

// Round 7
// 224.440 us; speedup vs baseline: 2.6677x; 1.0434x over previous
//
#include <hip/hip_runtime.h>

#define NUM_E 1024
#define DIM 64
#define NROWS 65536                  // 64*32*32
#define OUT0_SIZE 4194304            // 64*64*32*32
#define OUT1_OFF OUT0_SIZE
#define LOSS_OFF (OUT0_SIZE + 65536) // 4259840
#define KSPLIT 4
#define KCHUNK (NUM_E / KSPLIT)      // 256 codes per wave-slice

// ---------------- prep: En_k = np.sum(e_k*e_k) in numpy pairwise order ----
__device__ __forceinline__ float np_sumsq64_arr(const float* __restrict__ x) {
#pragma clang fp contract(off)
    float r[8];
#pragma unroll
    for (int j = 0; j < 8; ++j) r[j] = x[j] * x[j];
#pragma unroll
    for (int i = 8; i < 64; i += 8) {
#pragma unroll
        for (int j = 0; j < 8; ++j) {
            float p = x[i + j] * x[i + j];
            r[j] = r[j] + p;
        }
    }
    return ((r[0] + r[1]) + (r[2] + r[3])) + ((r[4] + r[5]) + (r[6] + r[7]));
}

__global__ __launch_bounds__(256) void vq_prep_kernel(const float* __restrict__ e,
                                                      float* __restrict__ En,
                                                      float* __restrict__ out) {
    const int k = blockIdx.x * 256 + threadIdx.x;   // grid covers 1024 exactly
    if (k == 0) out[LOSS_OFF] = 0.0f;               // d_out re-poisoned every call
    float xr[DIM];
    const float4* ep = (const float4*)(e + (size_t)k * DIM);
#pragma unroll
    for (int i = 0; i < 16; ++i) {
        float4 v = ep[i];
        xr[4*i+0] = v.x; xr[4*i+1] = v.y; xr[4*i+2] = v.z; xr[4*i+3] = v.w;
    }
    En[k] = np_sumsq64_arr(xr);
}

// ---------------- fused scan+finish ----------------
// Block = 256 threads = 4 waves over 64 rows. Wave q scans codes
// [q*256, (q+1)*256) -- q via readfirstlane so e addressing is formally
// uniform (s_load). z row lives in 16 named float4s; k-loop unroll 1 keeps
// e in-flight pressure at 64 floats so z is not the eviction victim (R4/R5
// failure mode: VGPR_Count=40, z re-loaded per k-iter from L1).
#define SQ8(A, B)                                              \
    { float p;                                                 \
      p = A.x*A.x; r0 = r0 + p;  p = A.y*A.y; r1 = r1 + p;     \
      p = A.z*A.z; r2 = r2 + p;  p = A.w*A.w; r3 = r3 + p;     \
      p = B.x*B.x; r4 = r4 + p;  p = B.y*B.y; r5 = r5 + p;     \
      p = B.z*B.z; r6 = r6 + p;  p = B.w*B.w; r7 = r7 + p; }

#define DOT4(Q, ZQ)                                            \
    { float4 ev = ep[Q];                                       \
      m = fmaf(ev.x, ZQ.x, m); m = fmaf(ev.y, ZQ.y, m);        \
      m = fmaf(ev.z, ZQ.z, m); m = fmaf(ev.w, ZQ.w, m); }

#define EPI4(Q, ZQ)                                            \
    { float4 evv = erp[Q]; float df;                           \
      o0[(size_t)(4*Q+0)*1024] = evv.x; df = evv.x - ZQ.x; lsum = fmaf(df,df,lsum); \
      o0[(size_t)(4*Q+1)*1024] = evv.y; df = evv.y - ZQ.y; lsum = fmaf(df,df,lsum); \
      o0[(size_t)(4*Q+2)*1024] = evv.z; df = evv.z - ZQ.z; lsum = fmaf(df,df,lsum); \
      o0[(size_t)(4*Q+3)*1024] = evv.w; df = evv.w - ZQ.w; lsum = fmaf(df,df,lsum); }

__global__ __launch_bounds__(256, 4) void vq_fused_kernel(const float* __restrict__ z,
                                                          const float* __restrict__ e,
                                                          const float* __restrict__ En,
                                                          float* __restrict__ out) {
    const int lane = threadIdx.x & 63;
    const int q = __builtin_amdgcn_readfirstlane((int)(threadIdx.x >> 6)); // wave-uniform slice id
    const int n = blockIdx.x * 64 + lane;            // row

    float4 z0,z1,z2,z3,z4,z5,z6,z7,z8,z9,z10,z11,z12,z13,z14,z15;
    {
        const float4* zp = (const float4*)(z + (size_t)n * DIM);
        z0=zp[0]; z1=zp[1]; z2=zp[2]; z3=zp[3]; z4=zp[4]; z5=zp[5]; z6=zp[6]; z7=zp[7];
        z8=zp[8]; z9=zp[9]; z10=zp[10]; z11=zp[11]; z12=zp[12]; z13=zp[13]; z14=zp[14]; z15=zp[15];
    }

    // A = np pairwise sum of z*z (bit-exact vs numpy, validated R3)
    float A;
    {
#pragma clang fp contract(off)
        float r0,r1,r2,r3,r4,r5,r6,r7;
        { float p;
          p = z0.x*z0.x; r0 = p;  p = z0.y*z0.y; r1 = p;
          p = z0.z*z0.z; r2 = p;  p = z0.w*z0.w; r3 = p;
          p = z1.x*z1.x; r4 = p;  p = z1.y*z1.y; r5 = p;
          p = z1.z*z1.z; r6 = p;  p = z1.w*z1.w; r7 = p; }
        SQ8(z2,  z3)  SQ8(z4,  z5)  SQ8(z6,  z7)
        SQ8(z8,  z9)  SQ8(z10, z11) SQ8(z12, z13) SQ8(z14, z15)
        A = ((r0 + r1) + (r2 + r3)) + ((r4 + r5) + (r6 + r7));
    }

    const int k0 = q * KCHUNK;
    float best = 3.4e38f;
    int bk = k0;
#pragma unroll 1
    for (int kk = 0; kk < KCHUNK; ++kk) {
        const int k = k0 + kk;
        const float4* ep = (const float4*)(e + (size_t)k * DIM);  // uniform -> s_load
        float m = 0.0f;                                  // sequential sgemm chain
        DOT4(0,  z0)  DOT4(1,  z1)  DOT4(2,  z2)  DOT4(3,  z3)
        DOT4(4,  z4)  DOT4(5,  z5)  DOT4(6,  z6)  DOT4(7,  z7)
        DOT4(8,  z8)  DOT4(9,  z9)  DOT4(10, z10) DOT4(11, z11)
        DOT4(12, z12) DOT4(13, z13) DOT4(14, z14) DOT4(15, z15)
        float s;
        {
#pragma clang fp contract(off)
            float twoM = 2.0f * m;                       // exact
            float t = A - twoM;                          // the ref's rounding grid
            s = t + En[k];
        }
        if (s < best) { best = s; bk = k; }              // strict < => first index
    }

    __shared__ float ls[KSPLIT][64];
    __shared__ int   li[KSPLIT][64];
    ls[q][lane] = best;
    li[q][lane] = bk;
    __syncthreads();

    if (threadIdx.x < 64) {                              // wave 0 does the epilogue
        float b0 = ls[0][lane];
        int   kb = li[0][lane];
#pragma unroll
        for (int qq = 1; qq < KSPLIT; ++qq) {
            float sq = ls[qq][lane];
            if (sq < b0) { b0 = sq; kb = li[qq][lane]; } // ascending q = ascending k
        }

        const int b  = n >> 10;      // H*W = 1024
        const int hw = n & 1023;
        const float4* erp = (const float4*)(e + (size_t)kb * DIM);  // L2-hot gather
        float* o0 = out + (size_t)b * 65536 + hw;        // out0[b, d, hw]
        float lsum = 0.0f;
        EPI4(0,  z0)  EPI4(1,  z1)  EPI4(2,  z2)  EPI4(3,  z3)
        EPI4(4,  z4)  EPI4(5,  z5)  EPI4(6,  z6)  EPI4(7,  z7)
        EPI4(8,  z8)  EPI4(9,  z9)  EPI4(10, z10) EPI4(11, z11)
        EPI4(12, z12) EPI4(13, z13) EPI4(14, z14) EPI4(15, z15)
        out[OUT1_OFF + n] = (float)kb;

#pragma unroll
        for (int off = 32; off > 0; off >>= 1)
            lsum += __shfl_down(lsum, off, 64);
        if (lane == 0)
            atomicAdd(&out[LOSS_OFF], lsum * (1.25f / 4194304.0f));
    }
}

extern "C" void kernel_launch(void* const* d_in, const int* in_sizes, int n_in,
                              void* d_out, int out_size, void* d_ws, size_t ws_size,
                              hipStream_t stream) {
    const float* z = (const float*)d_in[0];       // [65536, 64] fp32
    const float* e = (const float*)d_in[1];       // [1024, 64] fp32
    float* out = (float*)d_out;
    float* En  = (float*)d_ws;                    // 1024 fp32 norms (4 KB)

    vq_prep_kernel<<<NUM_E / 256, 256, 0, stream>>>(e, En, out);
    vq_fused_kernel<<<NROWS / 64, 256, 0, stream>>>(z, e, En, out);
}